// Round 2
// baseline (514.306 us; speedup 1.0000x reference)
//
#include <hip/hip_runtime.h>
#include <hip/hip_cooperative_groups.h>
#include <hip/hip_bf16.h>
#include <math.h>

namespace cg = cooperative_groups;

// DigitCaps routing. PROVEN: P/W/out all FP32; MFMA hi/lo split path correct
// (round 7: PASS absmax 1.95e-3). Round 8: agree -> MFMA, sgemm 512thr.
// Round 9: fused agree (tgemm+reduce_bc, G in LDS) -> 179 us.
// Round 10 (this): ONE cooperative kernel, grid 512x256, grid.sync at the 5
// phase boundaries. sgemm phase re-waved 8->4 with two chunks per wave
// (bit-identical summation order, 2x ILP). agree combine re-split
// (2 K-halves x 5 mt-halves) to shrink LDS 52.7->22 KB for co-residency.
// Legacy 6-launch path kept as fallback if cooperative launch errors.
//   P [256][9216] f32, W [1152][10][16][8] f32, out v [256][10][16] f32.

typedef __bf16 bf16x8 __attribute__((ext_vector_type(8)));
typedef float v4f __attribute__((ext_vector_type(4)));

#define GRID_BLKS 512

__device__ __forceinline__ float b2f(unsigned short u) {
    return __uint_as_float(((unsigned)u) << 16);
}
__device__ __forceinline__ unsigned short f2b(float f) {   // RNE, finite only
    unsigned x = __float_as_uint(f);
    return (unsigned short)((x + 0x7FFFu + ((x >> 16) & 1u)) >> 16);
}
__device__ __forceinline__ void split4(float4 x, unsigned short* h, unsigned short* l) {
    const float* xf = (const float*)&x;
    #pragma unroll
    for (int i = 0; i < 4; ++i) {
        h[i] = f2b(xf[i]);
        l[i] = f2b(xf[i] - b2f(h[i]));
    }
}
__device__ __forceinline__ uint2 pack4(const unsigned short* s) {
    uint2 w;
    w.x = s[0] | ((unsigned)s[1] << 16);
    w.y = s[2] | ((unsigned)s[3] << 16);
    return w;
}

// ---- phase-shared LDS (union keeps block LDS at 22 KB -> easy 2 blocks/CU) ----
union SMem {
    struct { unsigned short H[64 * 72]; unsigned short L[64 * 72]; } sp;   // 18432 B
    struct { float comb[8][64][4]; } sg;                                   // 8192 B
    struct {
        float partial[2][5][4][64];   // 10240 B  [mh][j][reg][lane]
        float G[160][18];             // 11520 B  [cd][ri-local] pad 16->18
        float part[4][10];
        float cl[2][10];
    } ag;                                                                  // 22000 B
};

// ---- P split tile (proven round-1 code, LDS via union) ----
__device__ __forceinline__ void split_p_tile(SMem& sm, int tile,
    const float4* __restrict__ P4, uint2* __restrict__ Ph, uint2* __restrict__ Pl,
    uint4* __restrict__ Pth, uint4* __restrict__ Ptl)
{
    const int tid = threadIdx.x;
    const int b0 = (tile & 3) * 64;
    const int k0 = (tile >> 2) * 64;
    #pragma unroll
    for (int j = 0; j < 4; ++j) {
        int idx = tid + j * 256;              // 0..1023
        int row = idx >> 4, col4 = idx & 15;  // b-local, k/4-local
        int g = (b0 + row) * 2304 + (k0 >> 2) + col4;
        unsigned short h[4], l[4];
        split4(P4[g], h, l);
        Ph[g] = pack4(h);
        Pl[g] = pack4(l);
        #pragma unroll
        for (int i = 0; i < 4; ++i) {
            sm.sp.H[(col4 * 4 + i) * 72 + row] = h[i];
            sm.sp.L[(col4 * 4 + i) * 72 + row] = l[i];
        }
    }
    __syncthreads();
    #pragma unroll
    for (int j = 0; j < 2; ++j) {
        int idx = tid + j * 256;              // 0..511
        int krow = idx >> 3, bcol = idx & 7;
        unsigned short h[8], l[8];
        #pragma unroll
        for (int i = 0; i < 8; ++i) {
            h[i] = sm.sp.H[krow * 72 + bcol * 8 + i];
            l[i] = sm.sp.L[krow * 72 + bcol * 8 + i];
        }
        uint4 wh, wl;
        wh.x = h[0] | ((unsigned)h[1] << 16); wh.y = h[2] | ((unsigned)h[3] << 16);
        wh.z = h[4] | ((unsigned)h[5] << 16); wh.w = h[6] | ((unsigned)h[7] << 16);
        wl.x = l[0] | ((unsigned)l[1] << 16); wl.y = l[2] | ((unsigned)l[3] << 16);
        wl.z = l[4] | ((unsigned)l[5] << 16); wl.w = l[6] | ((unsigned)l[7] << 16);
        Pth[(size_t)(k0 + krow) * 32 + (b0 >> 3) + bcol] = wh;
        Ptl[(size_t)(k0 + krow) * 32 + (b0 >> 3) + bcol] = wl;
    }
}

// ---- sgemm phase: 4 waves, each runs the ORIGINAL 8-wave chunks {w, w+4}
// into separate accs -> comb[8] slots identical to proven 512-thr kernel. ----
__device__ __forceinline__ void sgemm_phase(SMem& sm, int L,
    const uint4* __restrict__ Ah, const uint4* __restrict__ Al,
    const uint4* __restrict__ Bh, const uint4* __restrict__ Bl,
    uint2* __restrict__ vth, uint2* __restrict__ vtl,
    float* __restrict__ outb, int uniform, int last)
{
    const int tid = threadIdx.x;
    const int wave = tid >> 6, lane = tid & 63;   // wave in [0,4)
    const int lm = lane & 15, q = lane >> 4;
    const int c = L / 16, b0 = (L % 16) * 16;

    const uint4* Ahp = Ah + (size_t)(b0 + lm) * 1152 + q;
    const uint4* Alp = Al + (size_t)(b0 + lm) * 1152 + q;
    const uint4* Bhp = Bh + ((size_t)q * 10 + c) * 16 + lm;
    const uint4* Blp = Bl + ((size_t)q * 10 + c) * 16 + lm;

    v4f acc0 = {0.f, 0.f, 0.f, 0.f};
    v4f acc1 = {0.f, 0.f, 0.f, 0.f};
    const int kA = wave * 36, kB = (wave + 4) * 36;
    for (int t = 0; t < 36; ++t) {
        const size_t k0_ = kA + t, k1_ = kB + t;
        bf16x8 ah0 = __builtin_bit_cast(bf16x8, Ahp[k0_ * 4]);
        bf16x8 al0 = __builtin_bit_cast(bf16x8, Alp[k0_ * 4]);
        bf16x8 bh0 = __builtin_bit_cast(bf16x8, Bhp[k0_ * 640]);
        bf16x8 bl0 = __builtin_bit_cast(bf16x8, Blp[k0_ * 640]);
        bf16x8 ah1 = __builtin_bit_cast(bf16x8, Ahp[k1_ * 4]);
        bf16x8 al1 = __builtin_bit_cast(bf16x8, Alp[k1_ * 4]);
        bf16x8 bh1 = __builtin_bit_cast(bf16x8, Bhp[k1_ * 640]);
        bf16x8 bl1 = __builtin_bit_cast(bf16x8, Blp[k1_ * 640]);
        acc0 = __builtin_amdgcn_mfma_f32_16x16x32_bf16(ah0, bh0, acc0, 0, 0, 0);
        acc0 = __builtin_amdgcn_mfma_f32_16x16x32_bf16(ah0, bl0, acc0, 0, 0, 0);
        acc0 = __builtin_amdgcn_mfma_f32_16x16x32_bf16(al0, bh0, acc0, 0, 0, 0);
        acc1 = __builtin_amdgcn_mfma_f32_16x16x32_bf16(ah1, bh1, acc1, 0, 0, 0);
        acc1 = __builtin_amdgcn_mfma_f32_16x16x32_bf16(ah1, bl1, acc1, 0, 0, 0);
        acc1 = __builtin_amdgcn_mfma_f32_16x16x32_bf16(al1, bh1, acc1, 0, 0, 0);
    }
    #pragma unroll
    for (int r = 0; r < 4; ++r) {
        sm.sg.comb[wave][lane][r] = acc0[r];
        sm.sg.comb[wave + 4][lane][r] = acc1[r];
    }
    __syncthreads();
    if (wave == 0) {
        float s[4], sq[4];
        #pragma unroll
        for (int r = 0; r < 4; ++r) {
            s[r] = 0.f;
            #pragma unroll
            for (int w = 0; w < 8; ++w) s[r] += sm.sg.comb[w][lane][r];
            if (uniform) s[r] *= 0.1f;
            sq[r] = s[r] * s[r];
        }
        #pragma unroll
        for (int m = 1; m < 16; m <<= 1) {
            #pragma unroll
            for (int r = 0; r < 4; ++r) sq[r] += __shfl_xor(sq[r], m);
        }
        float v[4];
        #pragma unroll
        for (int r = 0; r < 4; ++r) {
            const float n = sq[r];
            v[r] = s[r] * sqrtf(n) / (1.0f + n);
        }
        if (!last) {
            unsigned short h[4], l[4];
            #pragma unroll
            for (int r = 0; r < 4; ++r) {
                h[r] = f2b(v[r]);
                l[r] = f2b(v[r] - b2f(h[r]));
            }
            const int o = (c * 16 + lm) * 64 + (b0 >> 2) + q;   // uint2 units
            vth[o] = pack4(h);
            vtl[o] = pack4(l);
        } else {
            #pragma unroll
            for (int r = 0; r < 4; ++r)
                outb[((b0 + q * 4 + r) * 10 + c) * 16 + lm] = v[r];
        }
    }
}

// ---- agree body: tgemm (K-split 2 x mt-split 5) + proven reduce_bc ----
__device__ __forceinline__ void agree_body(SMem& sm, int tile,
    const uint4* __restrict__ vth, const uint4* __restrict__ vtl,
    const uint4* __restrict__ Pth, const uint4* __restrict__ Ptl,
    const float* __restrict__ Wf, float* __restrict__ b_log,
    unsigned short* __restrict__ Bh, unsigned short* __restrict__ Bl, int first)
{
    const int tid = threadIdx.x;
    const int wave = tid >> 6, lane = tid & 63;
    const int lm = lane & 15, q = lane >> 4;
    const int n0 = tile * 16;
    const int kh = wave & 1, mh = wave >> 1;

    v4f acc[5];
    #pragma unroll
    for (int j = 0; j < 5; ++j) acc[j] = (v4f){0.f, 0.f, 0.f, 0.f};
    #pragma unroll
    for (int kx = 0; kx < 4; ++kx) {
        const int kk = kh * 4 + kx;
        bf16x8 bh_ = __builtin_bit_cast(bf16x8, Pth[(size_t)(n0 + lm) * 32 + kk * 4 + q]);
        bf16x8 bl_ = __builtin_bit_cast(bf16x8, Ptl[(size_t)(n0 + lm) * 32 + kk * 4 + q]);
        #pragma unroll
        for (int j = 0; j < 5; ++j) {
            const int mt = mh * 5 + j;
            bf16x8 ah = __builtin_bit_cast(bf16x8, vth[(size_t)(mt * 16 + lm) * 32 + kk * 4 + q]);
            bf16x8 al = __builtin_bit_cast(bf16x8, vtl[(size_t)(mt * 16 + lm) * 32 + kk * 4 + q]);
            acc[j] = __builtin_amdgcn_mfma_f32_16x16x32_bf16(ah, bh_, acc[j], 0, 0, 0);
            acc[j] = __builtin_amdgcn_mfma_f32_16x16x32_bf16(ah, bl_, acc[j], 0, 0, 0);
            acc[j] = __builtin_amdgcn_mfma_f32_16x16x32_bf16(al, bh_, acc[j], 0, 0, 0);
        }
    }
    if (kh) {
        #pragma unroll
        for (int j = 0; j < 5; ++j)
            #pragma unroll
            for (int r = 0; r < 4; ++r)
                sm.ag.partial[mh][j][r][lane] = acc[j][r];
    }
    __syncthreads();
    if (!kh) {
        #pragma unroll
        for (int j = 0; j < 5; ++j) {
            const int mt = mh * 5 + j;
            #pragma unroll
            for (int r = 0; r < 4; ++r) {
                float s_ = acc[j][r] + sm.ag.partial[mh][j][r][lane];
                sm.ag.G[mt * 16 + q * 4 + r][lm] = s_;    // G[cd][ri-local]
            }
        }
    }
    __syncthreads();

    // ---- reduce_bc phase (proven logic; 128 threads per r-row) ----
    const int rl = tid >> 7;        // 0..1 -> which r this half-block owns
    const int t = tid & 127;        // d*8+i
    const int r = (n0 >> 3) + rl;
    const int wid2 = tid >> 6;      // 0..3

    float wv[10], a[10];
    #pragma unroll
    for (int c = 0; c < 10; ++c) {
        wv[c] = Wf[((size_t)r * 10 + c) * 128 + t];
        float g = sm.ag.G[c * 16 + (t >> 3)][rl * 8 + (t & 7)];
        a[c] = wv[c] * g;
    }
    #pragma unroll
    for (int m = 1; m < 64; m <<= 1) {
        #pragma unroll
        for (int c = 0; c < 10; ++c) a[c] += __shfl_xor(a[c], m);
    }
    if (lane == 0) {
        #pragma unroll
        for (int c = 0; c < 10; ++c) sm.ag.part[wid2][c] = a[c];
    }
    __syncthreads();
    if (t < 10) {    // threads 0..9 (rl=0) and 128..137 (rl=1)
        float s_ = (sm.ag.part[rl * 2][t] + sm.ag.part[rl * 2 + 1][t]) * (1.0f / 256.0f);
        float bn = (first ? 0.f : b_log[r * 10 + t]) + s_;
        b_log[r * 10 + t] = bn;
        sm.ag.part[rl * 2][t] = bn;      // reuse as softmax scratch
    }
    __syncthreads();
    if (t < 10) {
        float mx = sm.ag.part[rl * 2][0];
        #pragma unroll
        for (int j = 1; j < 10; ++j) mx = fmaxf(mx, sm.ag.part[rl * 2][j]);
        float den = 0.f;
        #pragma unroll
        for (int j = 0; j < 10; ++j) den += __expf(sm.ag.part[rl * 2][j] - mx);
        sm.ag.cl[rl][t] = __expf(sm.ag.part[rl * 2][t] - mx) / den;
    }
    __syncthreads();
    #pragma unroll
    for (int c = 0; c < 10; ++c) {
        float x = sm.ag.cl[rl][c] * wv[c];
        unsigned short h = f2b(x);
        Bh[((size_t)r * 10 + c) * 128 + t] = h;
        Bl[((size_t)r * 10 + c) * 128 + t] = f2b(x - b2f(h));
    }
}

// ---- the whole pipeline as one cooperative kernel ----
__global__ __launch_bounds__(256, 2) void routing_kernel(
    const float4* __restrict__ P4, const float4* __restrict__ W4,
    char* __restrict__ wsb, float* __restrict__ outb)
{
    __shared__ SMem sm;
    float* b_log = (float*)(wsb + 0);
    uint2* vth   = (uint2*)(wsb + 131072);
    uint2* vtl   = (uint2*)(wsb + 262144);
    uint2* Ph    = (uint2*)(wsb + 393216);
    uint2* Pl    = (uint2*)(wsb + 5242880);
    uint4* Pth   = (uint4*)(wsb + 10485760);
    uint4* Ptl   = (uint4*)(wsb + 15728640);
    uint2* Wh    = (uint2*)(wsb + 20971520);
    uint2* Wl    = (uint2*)(wsb + 25165824);
    unsigned short* BhS = (unsigned short*)(wsb + 29360128);
    unsigned short* BlS = (unsigned short*)(wsb + 33554432);
    const float* Wf = (const float*)W4;
    const int bid = blockIdx.x;
    cg::grid_group grid = cg::this_grid();

    // ---- split phase: W grid-stride + P tiles ----
    for (int idx = bid * 256 + threadIdx.x; idx < 368640; idx += GRID_BLKS * 256) {
        unsigned short h[4], l[4];
        split4(W4[idx], h, l);
        Wh[idx] = pack4(h);
        Wl[idx] = pack4(l);
    }
    for (int tile = bid; tile < 576; tile += GRID_BLKS) {
        split_p_tile(sm, tile, P4, Ph, Pl, Pth, Ptl);
        __syncthreads();
    }
    grid.sync();

    for (int it = 0; it < 3; ++it) {
        const uint4* B4h = (it == 0) ? (const uint4*)Wh : (const uint4*)BhS;
        const uint4* B4l = (it == 0) ? (const uint4*)Wl : (const uint4*)BlS;
        if (bid < 160)
            sgemm_phase(sm, bid, (const uint4*)Ph, (const uint4*)Pl, B4h, B4l,
                        vth, vtl, outb, it == 0 ? 1 : 0, it == 2 ? 1 : 0);
        if (it == 2) break;
        grid.sync();
        for (int tile = bid; tile < 576; tile += GRID_BLKS) {
            agree_body(sm, tile, (const uint4*)vth, (const uint4*)vtl, Pth, Ptl,
                       Wf, b_log, BhS, BlS, it == 0 ? 1 : 0);
            __syncthreads();
        }
        grid.sync();
    }
}

// ============================================================================
// ---- legacy round-1 kernels kept as fallback if cooperative launch errors --
// ============================================================================

__global__ __launch_bounds__(256) void split_pw_kernel(
    const float4* __restrict__ P4, uint2* __restrict__ Ph, uint2* __restrict__ Pl,
    uint4* __restrict__ Pth, uint4* __restrict__ Ptl,
    const float4* __restrict__ W4, uint2* __restrict__ Wh, uint2* __restrict__ Wl)
{
    __shared__ SMem sm;
    const int tid = threadIdx.x;
    if (blockIdx.x >= 576) {   // W path
        const int idx = (blockIdx.x - 576) * 256 + tid;
        unsigned short h[4], l[4];
        split4(W4[idx], h, l);
        Wh[idx] = pack4(h);
        Wl[idx] = pack4(l);
        return;
    }
    split_p_tile(sm, blockIdx.x, P4, Ph, Pl, Pth, Ptl);
}

__global__ __launch_bounds__(256) void sgemm_legacy_kernel(
    const uint4* __restrict__ Ah, const uint4* __restrict__ Al,
    const uint4* __restrict__ Bh, const uint4* __restrict__ Bl,
    uint2* __restrict__ vth, uint2* __restrict__ vtl,
    float* __restrict__ outb, int uniform, int last)
{
    __shared__ SMem sm;
    sgemm_phase(sm, blockIdx.x, Ah, Al, Bh, Bl, vth, vtl, outb, uniform, last);
}

__global__ __launch_bounds__(256) void agree_legacy_kernel(
    const uint4* __restrict__ vth, const uint4* __restrict__ vtl,
    const uint4* __restrict__ Pth, const uint4* __restrict__ Ptl,
    const float* __restrict__ Wf, float* __restrict__ b_log,
    unsigned short* __restrict__ Bh, unsigned short* __restrict__ Bl, int first)
{
    __shared__ SMem sm;
    agree_body(sm, blockIdx.x, vth, vtl, Pth, Ptl, Wf, b_log, Bh, Bl, first);
}

extern "C" void kernel_launch(void* const* d_in, const int* in_sizes, int n_in,
                              void* d_out, int out_size, void* d_ws, size_t ws_size,
                              hipStream_t stream)
{
    const float4* P4 = (const float4*)d_in[0];
    const float4* W4 = (const float4*)d_in[1];
    char* wsb = (char*)d_ws;
    float* outb = (float*)d_out;

    void* args[4] = {(void*)&P4, (void*)&W4, (void*)&wsb, (void*)&outb};
    hipError_t err = hipLaunchCooperativeKernel((const void*)routing_kernel,
                                                dim3(GRID_BLKS), dim3(256),
                                                args, 0, stream);
    if (err == hipSuccess) return;

    // ---- fallback: round-1 proven 6-launch path ----
    float* b_log = (float*)(wsb + 0);
    uint2* vth   = (uint2*)(wsb + 131072);
    uint2* vtl   = (uint2*)(wsb + 262144);
    uint2* Ph    = (uint2*)(wsb + 393216);
    uint2* Pl    = (uint2*)(wsb + 5242880);
    uint4* Pth   = (uint4*)(wsb + 10485760);
    uint4* Ptl   = (uint4*)(wsb + 15728640);
    uint2* Wh    = (uint2*)(wsb + 20971520);
    uint2* Wl    = (uint2*)(wsb + 25165824);
    unsigned short* Bh = (unsigned short*)(wsb + 29360128);
    unsigned short* Bl = (unsigned short*)(wsb + 33554432);
    const float* Wf = (const float*)W4;

    split_pw_kernel<<<2016, 256, 0, stream>>>(P4, Ph, Pl, Pth, Ptl, W4, Wh, Wl);
    sgemm_legacy_kernel<<<160, 256, 0, stream>>>((const uint4*)Ph, (const uint4*)Pl,
                                                 (const uint4*)Wh, (const uint4*)Wl,
                                                 vth, vtl, outb, 1, 0);
    agree_legacy_kernel<<<576, 256, 0, stream>>>((const uint4*)vth, (const uint4*)vtl,
                                                 Pth, Ptl, Wf, b_log, Bh, Bl, 1);
    sgemm_legacy_kernel<<<160, 256, 0, stream>>>((const uint4*)Ph, (const uint4*)Pl,
                                                 (const uint4*)Bh, (const uint4*)Bl,
                                                 vth, vtl, outb, 0, 0);
    agree_legacy_kernel<<<576, 256, 0, stream>>>((const uint4*)vth, (const uint4*)vtl,
                                                 Pth, Ptl, Wf, b_log, Bh, Bl, 0);
    sgemm_legacy_kernel<<<160, 256, 0, stream>>>((const uint4*)Ph, (const uint4*)Pl,
                                                 (const uint4*)Bh, (const uint4*)Bl,
                                                 vth, vtl, outb, 0, 1);
}

// Round 3
// 200.117 us; speedup vs baseline: 2.5700x; 2.5700x over previous
//
#include <hip/hip_runtime.h>
#include <hip/hip_bf16.h>
#include <math.h>

// DigitCaps routing. PROVEN: P/W/out all FP32; MFMA hi/lo split path correct
// (round 7: PASS absmax 1.95e-3). Round 8: agree -> MFMA, sgemm 512thr.
// Round 9: fused agree (tgemm+reduce_bc, G in LDS), merged split -> 179 us.
// Round 10: cooperative single-kernel -> 449 us REGRESSION (grid.sync kills
//   per-XCD L2 reuse; FETCH 107 MB). Reverted.
// Round 11 (this): round-9 structure + sgemm block-level ksplit=2 (320 blocks,
//   all 256 CUs engaged). Cross-block combine in-kernel via device-scope
//   atomicAdd partials + flag; 2nd-to-flag block atomic-reads summed tile and
//   runs the proven squash/emit epilogue. Partials zeroed by split kernel.
//   P [256][9216] f32, W [1152][10][16][8] f32, out v [256][10][16] f32.

typedef __bf16 bf16x8 __attribute__((ext_vector_type(8)));
typedef float v4f __attribute__((ext_vector_type(4)));

__device__ __forceinline__ float b2f(unsigned short u) {
    return __uint_as_float(((unsigned)u) << 16);
}
__device__ __forceinline__ unsigned short f2b(float f) {   // RNE, finite only
    unsigned x = __float_as_uint(f);
    return (unsigned short)((x + 0x7FFFu + ((x >> 16) & 1u)) >> 16);
}
__device__ __forceinline__ void split4(float4 x, unsigned short* h, unsigned short* l) {
    const float* xf = (const float*)&x;
    #pragma unroll
    for (int i = 0; i < 4; ++i) {
        h[i] = f2b(xf[i]);
        l[i] = f2b(xf[i] - b2f(h[i]));
    }
}
__device__ __forceinline__ uint2 pack4(const unsigned short* s) {
    uint2 w;
    w.x = s[0] | ((unsigned)s[1] << 16);
    w.y = s[2] | ((unsigned)s[3] << 16);
    return w;
}

// ---- merged split: blocks [0,576) split P (64b x 64k tile each);
//      blocks [576,2016) split W elementwise. Also zeroes sgemm partial
//      buffers + flags (3 iters x 160 tiles).
__global__ __launch_bounds__(256) void split_pw_kernel(
    const float4* __restrict__ P4, uint2* __restrict__ Ph, uint2* __restrict__ Pl,
    uint4* __restrict__ Pth, uint4* __restrict__ Ptl,
    const float4* __restrict__ W4, uint2* __restrict__ Wh, uint2* __restrict__ Wl,
    float* __restrict__ sPartAll, int* __restrict__ flagsAll)
{
    __shared__ unsigned short ldsH[64 * 72];
    __shared__ unsigned short ldsL[64 * 72];
    const int tid = threadIdx.x;

    const int zi = blockIdx.x * 256 + tid;
    if (zi < 122880) sPartAll[zi] = 0.0f;      // 3 x 160 x 256 floats
    if (zi < 480) flagsAll[zi] = 0;            // 3 x 160 flags

    if (blockIdx.x >= 576) {   // ---- W path ----
        const int idx = (blockIdx.x - 576) * 256 + tid;    // 0..368639
        unsigned short h[4], l[4];
        split4(W4[idx], h, l);
        Wh[idx] = pack4(h);
        Wl[idx] = pack4(l);
        return;
    }

    // ---- P path ----
    const int b0 = (blockIdx.x & 3) * 64;
    const int k0 = (blockIdx.x >> 2) * 64;
    #pragma unroll
    for (int j = 0; j < 4; ++j) {
        int idx = tid + j * 256;              // 0..1023
        int row = idx >> 4, col4 = idx & 15;  // b-local, k/4-local
        int g = (b0 + row) * 2304 + (k0 >> 2) + col4;
        unsigned short h[4], l[4];
        split4(P4[g], h, l);
        Ph[g] = pack4(h);
        Pl[g] = pack4(l);
        #pragma unroll
        for (int i = 0; i < 4; ++i) {
            ldsH[(col4 * 4 + i) * 72 + row] = h[i];
            ldsL[(col4 * 4 + i) * 72 + row] = l[i];
        }
    }
    __syncthreads();
    #pragma unroll
    for (int j = 0; j < 2; ++j) {
        int idx = tid + j * 256;              // 0..511
        int krow = idx >> 3, bcol = idx & 7;
        unsigned short h[8], l[8];
        #pragma unroll
        for (int i = 0; i < 8; ++i) {
            h[i] = ldsH[krow * 72 + bcol * 8 + i];
            l[i] = ldsL[krow * 72 + bcol * 8 + i];
        }
        uint4 wh, wl;
        wh.x = h[0] | ((unsigned)h[1] << 16); wh.y = h[2] | ((unsigned)h[3] << 16);
        wh.z = h[4] | ((unsigned)h[5] << 16); wh.w = h[6] | ((unsigned)h[7] << 16);
        wl.x = l[0] | ((unsigned)l[1] << 16); wl.y = l[2] | ((unsigned)l[3] << 16);
        wl.z = l[4] | ((unsigned)l[5] << 16); wl.w = l[6] | ((unsigned)l[7] << 16);
        Pth[(size_t)(k0 + krow) * 32 + (b0 >> 3) + bcol] = wh;
        Ptl[(size_t)(k0 + krow) * 32 + (b0 >> 3) + bcol] = wl;
    }
}

// ---- MFMA s-GEMM + fused squash. Round-7-proven maps; now block ksplit=2:
// grid 320 = 160 (c,b0) pairs x 2 K-halves; 512 thr; wave owns 18-kk chunk
// (ks*8+wave). Partials combined cross-block via atomicAdd + flag; the
// 2nd-to-flag block atomic-reads the sum and runs the proven epilogue.
__global__ __launch_bounds__(512) void sgemm_kernel(
    const uint4* __restrict__ Ah, const uint4* __restrict__ Al,
    const uint4* __restrict__ Bh, const uint4* __restrict__ Bl,
    uint2* __restrict__ vth, uint2* __restrict__ vtl,
    float* __restrict__ outb, float* __restrict__ sPart,
    int* __restrict__ flags, int uniform, int last)
{
    __shared__ float comb[8][64][4];
    const int tid = threadIdx.x;
    const int wave = tid >> 6, lane = tid & 63;
    const int lm = lane & 15, q = lane >> 4;
    const int pair = blockIdx.x >> 1, ks = blockIdx.x & 1;
    const int c = pair / 16, b0 = (pair % 16) * 16;

    const uint4* Ahp = Ah + (size_t)(b0 + lm) * 1152 + q;
    const uint4* Alp = Al + (size_t)(b0 + lm) * 1152 + q;
    const uint4* Bhp = Bh + ((size_t)q * 10 + c) * 16 + lm;
    const uint4* Blp = Bl + ((size_t)q * 10 + c) * 16 + lm;

    v4f acc = {0.f, 0.f, 0.f, 0.f};
    const int kk0 = (ks * 8 + wave) * 18;     // 16 chunks x 18 kk = 288
    for (int kk = kk0; kk < kk0 + 18; ++kk) {
        bf16x8 ah = __builtin_bit_cast(bf16x8, Ahp[(size_t)kk * 4]);
        bf16x8 al = __builtin_bit_cast(bf16x8, Alp[(size_t)kk * 4]);
        bf16x8 bh = __builtin_bit_cast(bf16x8, Bhp[(size_t)kk * 640]);
        bf16x8 bl = __builtin_bit_cast(bf16x8, Blp[(size_t)kk * 640]);
        acc = __builtin_amdgcn_mfma_f32_16x16x32_bf16(ah, bh, acc, 0, 0, 0);
        acc = __builtin_amdgcn_mfma_f32_16x16x32_bf16(ah, bl, acc, 0, 0, 0);
        acc = __builtin_amdgcn_mfma_f32_16x16x32_bf16(al, bh, acc, 0, 0, 0);
    }
    #pragma unroll
    for (int r = 0; r < 4; ++r) comb[wave][lane][r] = acc[r];
    __syncthreads();
    if (wave != 0) return;

    // within-block combine of 8 wave chunks
    float s[4];
    #pragma unroll
    for (int r = 0; r < 4; ++r) {
        s[r] = 0.f;
        #pragma unroll
        for (int w = 0; w < 8; ++w) s[r] += comb[w][lane][r];
    }
    // cross-block combine: add partial, then flag; 2nd flagger finishes
    const int base = pair * 256 + lane * 4;
    #pragma unroll
    for (int r = 0; r < 4; ++r) atomicAdd(&sPart[base + r], s[r]);
    __threadfence();
    int oldf = 0;
    if (lane == 0) oldf = atomicAdd(&flags[pair], 1);
    oldf = __shfl(oldf, 0);
    if (oldf == 0) return;

    // finisher: device-coherent read of the completed sum
    float sf[4], sq[4];
    #pragma unroll
    for (int r = 0; r < 4; ++r) {
        sf[r] = atomicAdd(&sPart[base + r], 0.0f);
        if (uniform) sf[r] *= 0.1f;
        sq[r] = sf[r] * sf[r];
    }
    #pragma unroll
    for (int m = 1; m < 16; m <<= 1) {
        #pragma unroll
        for (int r = 0; r < 4; ++r) sq[r] += __shfl_xor(sq[r], m);
    }
    float v[4];
    #pragma unroll
    for (int r = 0; r < 4; ++r) {
        const float n = sq[r];
        v[r] = sf[r] * sqrtf(n) / (1.0f + n);
    }
    if (!last) {
        unsigned short h[4], l[4];
        #pragma unroll
        for (int r = 0; r < 4; ++r) {
            h[r] = f2b(v[r]);
            l[r] = f2b(v[r] - b2f(h[r]));
        }
        const int o = (c * 16 + lm) * 64 + (b0 >> 2) + q;   // uint2 units
        vth[o] = pack4(h);
        vtl[o] = pack4(l);
    } else {
        #pragma unroll
        for (int r = 0; r < 4; ++r)
            outb[((b0 + q * 4 + r) * 10 + c) * 16 + lm] = v[r];
    }
}

// ---- agree: fused tgemm + reduce_bc (round-9-proven). One block per 16-ri
// tile (n0 = bid*16, covering r = 2*bid, 2*bid+1). 4 waves split K=256 ->
// 2 kk-steps each; partials summed via LDS; G kept in LDS; then reduce_bc
// runs on the two r-rows with 128 threads each; emits Bc hi/lo + b_log.
__global__ __launch_bounds__(256) void agree_kernel(
    const uint4* __restrict__ vth, const uint4* __restrict__ vtl,
    const uint4* __restrict__ Pth, const uint4* __restrict__ Ptl,
    const float* __restrict__ Wf, float* __restrict__ b_log,
    unsigned short* __restrict__ Bh, unsigned short* __restrict__ Bl, int first)
{
    __shared__ float comb2[40][4][64];   // [mt*4+reg][wave][lane] - conflict-free
    __shared__ float G_lds[160][18];     // [cd][ri-local], pad 16->18
    __shared__ float part[4][10];
    __shared__ float cl[2][10];
    const int tid = threadIdx.x;
    const int wave = tid >> 6, lane = tid & 63;
    const int lm = lane & 15, q = lane >> 4;
    const int n0 = blockIdx.x * 16;

    // ---- K-split tgemm: wave handles kk in {2*wave, 2*wave+1} ----
    v4f acc[10];
    #pragma unroll
    for (int mt = 0; mt < 10; ++mt) acc[mt] = (v4f){0.f, 0.f, 0.f, 0.f};
    #pragma unroll
    for (int kx = 0; kx < 2; ++kx) {
        const int kk = wave * 2 + kx;
        bf16x8 bh_ = __builtin_bit_cast(bf16x8, Pth[(size_t)(n0 + lm) * 32 + kk * 4 + q]);
        bf16x8 bl_ = __builtin_bit_cast(bf16x8, Ptl[(size_t)(n0 + lm) * 32 + kk * 4 + q]);
        #pragma unroll
        for (int mt = 0; mt < 10; ++mt) {
            bf16x8 ah = __builtin_bit_cast(bf16x8, vth[(size_t)(mt * 16 + lm) * 32 + kk * 4 + q]);
            bf16x8 al = __builtin_bit_cast(bf16x8, vtl[(size_t)(mt * 16 + lm) * 32 + kk * 4 + q]);
            acc[mt] = __builtin_amdgcn_mfma_f32_16x16x32_bf16(ah, bh_, acc[mt], 0, 0, 0);
            acc[mt] = __builtin_amdgcn_mfma_f32_16x16x32_bf16(ah, bl_, acc[mt], 0, 0, 0);
            acc[mt] = __builtin_amdgcn_mfma_f32_16x16x32_bf16(al, bh_, acc[mt], 0, 0, 0);
        }
    }
    #pragma unroll
    for (int mt = 0; mt < 10; ++mt)
        #pragma unroll
        for (int r = 0; r < 4; ++r)
            comb2[mt * 4 + r][wave][lane] = acc[mt][r];
    __syncthreads();
    // ---- sum wave partials -> G_lds. Wave w owns c40 = w*10 .. w*10+9 ----
    #pragma unroll
    for (int j = 0; j < 10; ++j) {
        const int c40 = wave * 10 + j;
        float s_ = comb2[c40][0][lane] + comb2[c40][1][lane]
                 + comb2[c40][2][lane] + comb2[c40][3][lane];
        const int mt = c40 >> 2, reg = c40 & 3;
        G_lds[mt * 16 + q * 4 + reg][lm] = s_;     // G[cd][ri = n0+lm]
    }
    __syncthreads();

    // ---- reduce_bc phase (proven logic; 128 threads per r-row) ----
    const int rl = tid >> 7;        // 0..1 -> which r this half-block owns
    const int t = tid & 127;        // d*8+i
    const int r = (n0 >> 3) + rl;
    const int wid2 = tid >> 6;      // 0..3

    float wv[10], a[10];
    #pragma unroll
    for (int c = 0; c < 10; ++c) {
        wv[c] = Wf[((size_t)r * 10 + c) * 128 + t];
        float g = G_lds[c * 16 + (t >> 3)][rl * 8 + (t & 7)];
        a[c] = wv[c] * g;
    }
    #pragma unroll
    for (int m = 1; m < 64; m <<= 1) {
        #pragma unroll
        for (int c = 0; c < 10; ++c) a[c] += __shfl_xor(a[c], m);
    }
    if (lane == 0) {
        #pragma unroll
        for (int c = 0; c < 10; ++c) part[wid2][c] = a[c];
    }
    __syncthreads();
    if (t < 10) {    // threads 0..9 (rl=0) and 128..137 (rl=1)
        float s_ = (part[rl * 2][t] + part[rl * 2 + 1][t]) * (1.0f / 256.0f);
        float bn = (first ? 0.f : b_log[r * 10 + t]) + s_;
        b_log[r * 10 + t] = bn;
        part[rl * 2][t] = bn;            // reuse as softmax scratch
    }
    __syncthreads();
    if (t < 10) {
        float mx = part[rl * 2][0];
        #pragma unroll
        for (int j = 1; j < 10; ++j) mx = fmaxf(mx, part[rl * 2][j]);
        float den = 0.f;
        #pragma unroll
        for (int j = 0; j < 10; ++j) den += __expf(part[rl * 2][j] - mx);
        cl[rl][t] = __expf(part[rl * 2][t] - mx) / den;
    }
    __syncthreads();
    #pragma unroll
    for (int c = 0; c < 10; ++c) {
        float x = cl[rl][c] * wv[c];
        unsigned short h = f2b(x);
        Bh[((size_t)r * 10 + c) * 128 + t] = h;
        Bl[((size_t)r * 10 + c) * 128 + t] = f2b(x - b2f(h));
    }
}

extern "C" void kernel_launch(void* const* d_in, const int* in_sizes, int n_in,
                              void* d_out, int out_size, void* d_ws, size_t ws_size,
                              hipStream_t stream)
{
    const float4* P4 = (const float4*)d_in[0];
    const float4* W4 = (const float4*)d_in[1];
    char* wsb = (char*)d_ws;
    // BYTE offsets (audited, all 16B-aligned):
    float* b_log = (float*)(wsb + 0);              // 46080 B
    uint2* vth   = (uint2*)(wsb + 131072);         // 81920 B
    uint2* vtl   = (uint2*)(wsb + 262144);         // 81920 B
    uint2* Ph    = (uint2*)(wsb + 393216);         // 4718592 B
    uint2* Pl    = (uint2*)(wsb + 5242880);        // 4718592 B
    uint4* Pth   = (uint4*)(wsb + 10485760);       // 4718592 B
    uint4* Ptl   = (uint4*)(wsb + 15728640);       // 4718592 B
    uint2* Wh    = (uint2*)(wsb + 20971520);       // 2949120 B
    uint2* Wl    = (uint2*)(wsb + 25165824);       // 2949120 B
    unsigned short* Bh = (unsigned short*)(wsb + 29360128);  // 2949120 B
    unsigned short* Bl = (unsigned short*)(wsb + 33554432);  // 2949120 B
    float* sPart = (float*)(wsb + 37748736);       // 3 x 163840 B
    int*   flags = (int*)(wsb + 38240256);         // 3 x 640 B
    float* outb  = (float*)d_out;
    const float* Wf = (const float*)W4;

    split_pw_kernel<<<2016, 256, 0, stream>>>(P4, Ph, Pl, Pth, Ptl, W4, Wh, Wl,
                                              sPart, flags);

    // iter 0: B = W, uniform c = 0.1 post-MFMA
    sgemm_kernel<<<320, 512, 0, stream>>>((const uint4*)Ph, (const uint4*)Pl,
                                          (const uint4*)Wh, (const uint4*)Wl,
                                          vth, vtl, outb,
                                          sPart, flags, 1, 0);
    agree_kernel<<<576, 256, 0, stream>>>((const uint4*)vth, (const uint4*)vtl,
                                          Pth, Ptl, Wf, b_log, Bh, Bl, 1);
    // iter 1
    sgemm_kernel<<<320, 512, 0, stream>>>((const uint4*)Ph, (const uint4*)Pl,
                                          (const uint4*)Bh, (const uint4*)Bl,
                                          vth, vtl, outb,
                                          sPart + 40960, flags + 160, 0, 0);
    agree_kernel<<<576, 256, 0, stream>>>((const uint4*)vth, (const uint4*)vtl,
                                          Pth, Ptl, Wf, b_log, Bh, Bl, 0);
    // iter 2 -> d_out
    sgemm_kernel<<<320, 512, 0, stream>>>((const uint4*)Ph, (const uint4*)Pl,
                                          (const uint4*)Bh, (const uint4*)Bl,
                                          vth, vtl, outb,
                                          sPart + 81920, flags + 320, 0, 1);
}

// Round 4
// 184.345 us; speedup vs baseline: 2.7899x; 1.0856x over previous
//
#include <hip/hip_runtime.h>
#include <hip/hip_bf16.h>
#include <math.h>

// DigitCaps routing. PROVEN: P/W/out all FP32; MFMA hi/lo split path correct
// (round 7: PASS absmax 1.95e-3). Round 8: agree -> MFMA, sgemm 512thr.
// Round 9: fused agree (tgemm+reduce_bc, G in LDS), merged split -> 179 us.
// Round 10: cooperative single-kernel -> 449 us REGRESSION (grid.sync kills
//   per-XCD L2 reuse; FETCH 107 MB). Reverted.
// Round 11: sgemm block-ksplit=2 + atomic combine -> 200 us REGRESSION
//   (cross-block combine overhead > parallelism gain at this problem size).
// Round 12 (this): round-9 structure exactly, EXCEPT sgemm inner loop gets
//   2 independent K-streams per wave (chunks w and w+8, 18 kk each) ->
//   2x memory-level parallelism in the latency-bound loop. comb[16] epilogue
//   sum is an fp32 re-association only (delta ~1e-7 << 2e-3 bf16 floor).
//   P [256][9216] f32, W [1152][10][16][8] f32, out v [256][10][16] f32.

typedef __bf16 bf16x8 __attribute__((ext_vector_type(8)));
typedef float v4f __attribute__((ext_vector_type(4)));

__device__ __forceinline__ float b2f(unsigned short u) {
    return __uint_as_float(((unsigned)u) << 16);
}
__device__ __forceinline__ unsigned short f2b(float f) {   // RNE, finite only
    unsigned x = __float_as_uint(f);
    return (unsigned short)((x + 0x7FFFu + ((x >> 16) & 1u)) >> 16);
}
__device__ __forceinline__ void split4(float4 x, unsigned short* h, unsigned short* l) {
    const float* xf = (const float*)&x;
    #pragma unroll
    for (int i = 0; i < 4; ++i) {
        h[i] = f2b(xf[i]);
        l[i] = f2b(xf[i] - b2f(h[i]));
    }
}
__device__ __forceinline__ uint2 pack4(const unsigned short* s) {
    uint2 w;
    w.x = s[0] | ((unsigned)s[1] << 16);
    w.y = s[2] | ((unsigned)s[3] << 16);
    return w;
}

// ---- merged split: blocks [0,576) split P (64b x 64k tile each);
//      blocks [576,2016) split W elementwise.
__global__ __launch_bounds__(256) void split_pw_kernel(
    const float4* __restrict__ P4, uint2* __restrict__ Ph, uint2* __restrict__ Pl,
    uint4* __restrict__ Pth, uint4* __restrict__ Ptl,
    const float4* __restrict__ W4, uint2* __restrict__ Wh, uint2* __restrict__ Wl)
{
    __shared__ unsigned short ldsH[64 * 72];
    __shared__ unsigned short ldsL[64 * 72];
    const int tid = threadIdx.x;

    if (blockIdx.x >= 576) {   // ---- W path ----
        const int idx = (blockIdx.x - 576) * 256 + tid;    // 0..368639
        unsigned short h[4], l[4];
        split4(W4[idx], h, l);
        Wh[idx] = pack4(h);
        Wl[idx] = pack4(l);
        return;
    }

    // ---- P path ----
    const int b0 = (blockIdx.x & 3) * 64;
    const int k0 = (blockIdx.x >> 2) * 64;
    #pragma unroll
    for (int j = 0; j < 4; ++j) {
        int idx = tid + j * 256;              // 0..1023
        int row = idx >> 4, col4 = idx & 15;  // b-local, k/4-local
        int g = (b0 + row) * 2304 + (k0 >> 2) + col4;
        unsigned short h[4], l[4];
        split4(P4[g], h, l);
        Ph[g] = pack4(h);
        Pl[g] = pack4(l);
        #pragma unroll
        for (int i = 0; i < 4; ++i) {
            ldsH[(col4 * 4 + i) * 72 + row] = h[i];
            ldsL[(col4 * 4 + i) * 72 + row] = l[i];
        }
    }
    __syncthreads();
    #pragma unroll
    for (int j = 0; j < 2; ++j) {
        int idx = tid + j * 256;              // 0..511
        int krow = idx >> 3, bcol = idx & 7;
        unsigned short h[8], l[8];
        #pragma unroll
        for (int i = 0; i < 8; ++i) {
            h[i] = ldsH[krow * 72 + bcol * 8 + i];
            l[i] = ldsL[krow * 72 + bcol * 8 + i];
        }
        uint4 wh, wl;
        wh.x = h[0] | ((unsigned)h[1] << 16); wh.y = h[2] | ((unsigned)h[3] << 16);
        wh.z = h[4] | ((unsigned)h[5] << 16); wh.w = h[6] | ((unsigned)h[7] << 16);
        wl.x = l[0] | ((unsigned)l[1] << 16); wl.y = l[2] | ((unsigned)l[3] << 16);
        wl.z = l[4] | ((unsigned)l[5] << 16); wl.w = l[6] | ((unsigned)l[7] << 16);
        Pth[(size_t)(k0 + krow) * 32 + (b0 >> 3) + bcol] = wh;
        Ptl[(size_t)(k0 + krow) * 32 + (b0 >> 3) + bcol] = wl;
    }
}

// ---- MFMA s-GEMM + fused squash (round-7-proven maps; 512 thr).
// Round 12: each wave runs TWO independent 18-kk K-streams (chunks w, w+8)
// for 2x loads-in-flight; comb[16] epilogue (fp32 re-association only).
// Writes v transposed hi/lo (vt[cd][b]) for agree A; last iter writes outb.
__global__ __launch_bounds__(512) void sgemm_kernel(
    const uint4* __restrict__ Ah, const uint4* __restrict__ Al,
    const uint4* __restrict__ Bh, const uint4* __restrict__ Bl,
    uint2* __restrict__ vth, uint2* __restrict__ vtl,
    float* __restrict__ outb, int uniform, int last)
{
    __shared__ float comb[16][64][4];
    const int tid = threadIdx.x;
    const int wave = tid >> 6, lane = tid & 63;
    const int lm = lane & 15, q = lane >> 4;
    const int c = blockIdx.x / 16, b0 = (blockIdx.x % 16) * 16;

    const uint4* Ahp = Ah + (size_t)(b0 + lm) * 1152 + q;
    const uint4* Alp = Al + (size_t)(b0 + lm) * 1152 + q;
    const uint4* Bhp = Bh + ((size_t)q * 10 + c) * 16 + lm;
    const uint4* Blp = Bl + ((size_t)q * 10 + c) * 16 + lm;

    v4f acc0 = {0.f, 0.f, 0.f, 0.f};
    v4f acc1 = {0.f, 0.f, 0.f, 0.f};
    const int kA = wave * 18, kB = (wave + 8) * 18;   // 16 chunks x 18 kk = 288
    for (int t = 0; t < 18; ++t) {
        const size_t k0_ = (size_t)(kA + t), k1_ = (size_t)(kB + t);
        bf16x8 ah0 = __builtin_bit_cast(bf16x8, Ahp[k0_ * 4]);
        bf16x8 al0 = __builtin_bit_cast(bf16x8, Alp[k0_ * 4]);
        bf16x8 bh0 = __builtin_bit_cast(bf16x8, Bhp[k0_ * 640]);
        bf16x8 bl0 = __builtin_bit_cast(bf16x8, Blp[k0_ * 640]);
        bf16x8 ah1 = __builtin_bit_cast(bf16x8, Ahp[k1_ * 4]);
        bf16x8 al1 = __builtin_bit_cast(bf16x8, Alp[k1_ * 4]);
        bf16x8 bh1 = __builtin_bit_cast(bf16x8, Bhp[k1_ * 640]);
        bf16x8 bl1 = __builtin_bit_cast(bf16x8, Blp[k1_ * 640]);
        acc0 = __builtin_amdgcn_mfma_f32_16x16x32_bf16(ah0, bh0, acc0, 0, 0, 0);
        acc0 = __builtin_amdgcn_mfma_f32_16x16x32_bf16(ah0, bl0, acc0, 0, 0, 0);
        acc0 = __builtin_amdgcn_mfma_f32_16x16x32_bf16(al0, bh0, acc0, 0, 0, 0);
        acc1 = __builtin_amdgcn_mfma_f32_16x16x32_bf16(ah1, bh1, acc1, 0, 0, 0);
        acc1 = __builtin_amdgcn_mfma_f32_16x16x32_bf16(ah1, bl1, acc1, 0, 0, 0);
        acc1 = __builtin_amdgcn_mfma_f32_16x16x32_bf16(al1, bh1, acc1, 0, 0, 0);
    }
    #pragma unroll
    for (int r = 0; r < 4; ++r) {
        comb[wave][lane][r] = acc0[r];
        comb[wave + 8][lane][r] = acc1[r];
    }
    __syncthreads();
    if (wave == 0) {
        float s[4], sq[4];
        #pragma unroll
        for (int r = 0; r < 4; ++r) {
            s[r] = 0.f;
            #pragma unroll
            for (int w = 0; w < 16; ++w) s[r] += comb[w][lane][r];
            if (uniform) s[r] *= 0.1f;
            sq[r] = s[r] * s[r];
        }
        #pragma unroll
        for (int m = 1; m < 16; m <<= 1) {
            #pragma unroll
            for (int r = 0; r < 4; ++r) sq[r] += __shfl_xor(sq[r], m);
        }
        float v[4];
        #pragma unroll
        for (int r = 0; r < 4; ++r) {
            const float n = sq[r];
            v[r] = s[r] * sqrtf(n) / (1.0f + n);
        }
        if (!last) {
            unsigned short h[4], l[4];
            #pragma unroll
            for (int r = 0; r < 4; ++r) {
                h[r] = f2b(v[r]);
                l[r] = f2b(v[r] - b2f(h[r]));
            }
            const int o = (c * 16 + lm) * 64 + (b0 >> 2) + q;   // uint2 units
            vth[o] = pack4(h);
            vtl[o] = pack4(l);
        } else {
            #pragma unroll
            for (int r = 0; r < 4; ++r)
                outb[((b0 + q * 4 + r) * 10 + c) * 16 + lm] = v[r];
        }
    }
}

// ---- agree: fused tgemm + reduce_bc (round-9-proven). One block per 16-ri
// tile (n0 = bid*16, covering r = 2*bid, 2*bid+1). 4 waves split K=256 ->
// 2 kk-steps each; partials summed via LDS; G kept in LDS; then reduce_bc
// runs on the two r-rows with 128 threads each; emits Bc hi/lo + b_log.
__global__ __launch_bounds__(256) void agree_kernel(
    const uint4* __restrict__ vth, const uint4* __restrict__ vtl,
    const uint4* __restrict__ Pth, const uint4* __restrict__ Ptl,
    const float* __restrict__ Wf, float* __restrict__ b_log,
    unsigned short* __restrict__ Bh, unsigned short* __restrict__ Bl, int first)
{
    __shared__ float comb2[40][4][64];   // [mt*4+reg][wave][lane] - conflict-free
    __shared__ float G_lds[160][18];     // [cd][ri-local], pad 16->18
    __shared__ float part[4][10];
    __shared__ float cl[2][10];
    const int tid = threadIdx.x;
    const int wave = tid >> 6, lane = tid & 63;
    const int lm = lane & 15, q = lane >> 4;
    const int n0 = blockIdx.x * 16;

    // ---- K-split tgemm: wave handles kk in {2*wave, 2*wave+1} ----
    v4f acc[10];
    #pragma unroll
    for (int mt = 0; mt < 10; ++mt) acc[mt] = (v4f){0.f, 0.f, 0.f, 0.f};
    #pragma unroll
    for (int kx = 0; kx < 2; ++kx) {
        const int kk = wave * 2 + kx;
        bf16x8 bh_ = __builtin_bit_cast(bf16x8, Pth[(size_t)(n0 + lm) * 32 + kk * 4 + q]);
        bf16x8 bl_ = __builtin_bit_cast(bf16x8, Ptl[(size_t)(n0 + lm) * 32 + kk * 4 + q]);
        #pragma unroll
        for (int mt = 0; mt < 10; ++mt) {
            bf16x8 ah = __builtin_bit_cast(bf16x8, vth[(size_t)(mt * 16 + lm) * 32 + kk * 4 + q]);
            bf16x8 al = __builtin_bit_cast(bf16x8, vtl[(size_t)(mt * 16 + lm) * 32 + kk * 4 + q]);
            acc[mt] = __builtin_amdgcn_mfma_f32_16x16x32_bf16(ah, bh_, acc[mt], 0, 0, 0);
            acc[mt] = __builtin_amdgcn_mfma_f32_16x16x32_bf16(ah, bl_, acc[mt], 0, 0, 0);
            acc[mt] = __builtin_amdgcn_mfma_f32_16x16x32_bf16(al, bh_, acc[mt], 0, 0, 0);
        }
    }
    #pragma unroll
    for (int mt = 0; mt < 10; ++mt)
        #pragma unroll
        for (int r = 0; r < 4; ++r)
            comb2[mt * 4 + r][wave][lane] = acc[mt][r];
    __syncthreads();
    // ---- sum wave partials -> G_lds. Wave w owns c40 = w*10 .. w*10+9 ----
    #pragma unroll
    for (int j = 0; j < 10; ++j) {
        const int c40 = wave * 10 + j;
        float s_ = comb2[c40][0][lane] + comb2[c40][1][lane]
                 + comb2[c40][2][lane] + comb2[c40][3][lane];
        const int mt = c40 >> 2, reg = c40 & 3;
        G_lds[mt * 16 + q * 4 + reg][lm] = s_;     // G[cd][ri = n0+lm]
    }
    __syncthreads();

    // ---- reduce_bc phase (proven logic; 128 threads per r-row) ----
    const int rl = tid >> 7;        // 0..1 -> which r this half-block owns
    const int t = tid & 127;        // d*8+i
    const int r = (n0 >> 3) + rl;
    const int wid2 = tid >> 6;      // 0..3

    float wv[10], a[10];
    #pragma unroll
    for (int c = 0; c < 10; ++c) {
        wv[c] = Wf[((size_t)r * 10 + c) * 128 + t];
        float g = G_lds[c * 16 + (t >> 3)][rl * 8 + (t & 7)];
        a[c] = wv[c] * g;
    }
    #pragma unroll
    for (int m = 1; m < 64; m <<= 1) {
        #pragma unroll
        for (int c = 0; c < 10; ++c) a[c] += __shfl_xor(a[c], m);
    }
    if (lane == 0) {
        #pragma unroll
        for (int c = 0; c < 10; ++c) part[wid2][c] = a[c];
    }
    __syncthreads();
    if (t < 10) {    // threads 0..9 (rl=0) and 128..137 (rl=1)
        float s_ = (part[rl * 2][t] + part[rl * 2 + 1][t]) * (1.0f / 256.0f);
        float bn = (first ? 0.f : b_log[r * 10 + t]) + s_;
        b_log[r * 10 + t] = bn;
        part[rl * 2][t] = bn;            // reuse as softmax scratch
    }
    __syncthreads();
    if (t < 10) {
        float mx = part[rl * 2][0];
        #pragma unroll
        for (int j = 1; j < 10; ++j) mx = fmaxf(mx, part[rl * 2][j]);
        float den = 0.f;
        #pragma unroll
        for (int j = 0; j < 10; ++j) den += __expf(part[rl * 2][j] - mx);
        cl[rl][t] = __expf(part[rl * 2][t] - mx) / den;
    }
    __syncthreads();
    #pragma unroll
    for (int c = 0; c < 10; ++c) {
        float x = cl[rl][c] * wv[c];
        unsigned short h = f2b(x);
        Bh[((size_t)r * 10 + c) * 128 + t] = h;
        Bl[((size_t)r * 10 + c) * 128 + t] = f2b(x - b2f(h));
    }
}

extern "C" void kernel_launch(void* const* d_in, const int* in_sizes, int n_in,
                              void* d_out, int out_size, void* d_ws, size_t ws_size,
                              hipStream_t stream)
{
    const float4* P4 = (const float4*)d_in[0];
    const float4* W4 = (const float4*)d_in[1];
    char* wsb = (char*)d_ws;
    // BYTE offsets (audited, all 16B-aligned):
    float* b_log = (float*)(wsb + 0);              // 46080 B
    uint2* vth   = (uint2*)(wsb + 131072);         // 81920 B
    uint2* vtl   = (uint2*)(wsb + 262144);         // 81920 B
    uint2* Ph    = (uint2*)(wsb + 393216);         // 4718592 B
    uint2* Pl    = (uint2*)(wsb + 5242880);        // 4718592 B
    uint4* Pth   = (uint4*)(wsb + 10485760);       // 4718592 B
    uint4* Ptl   = (uint4*)(wsb + 15728640);       // 4718592 B
    uint2* Wh    = (uint2*)(wsb + 20971520);       // 2949120 B
    uint2* Wl    = (uint2*)(wsb + 25165824);       // 2949120 B
    unsigned short* Bh = (unsigned short*)(wsb + 29360128);  // 2949120 B
    unsigned short* Bl = (unsigned short*)(wsb + 33554432);  // 2949120 B
    float* outb  = (float*)d_out;
    const float* Wf = (const float*)W4;

    split_pw_kernel<<<2016, 256, 0, stream>>>(P4, Ph, Pl, Pth, Ptl, W4, Wh, Wl);

    // iter 0: B = W, uniform c = 0.1 post-MFMA
    sgemm_kernel<<<160, 512, 0, stream>>>((const uint4*)Ph, (const uint4*)Pl,
                                          (const uint4*)Wh, (const uint4*)Wl,
                                          vth, vtl, outb, 1, 0);
    agree_kernel<<<576, 256, 0, stream>>>((const uint4*)vth, (const uint4*)vtl,
                                          Pth, Ptl, Wf, b_log, Bh, Bl, 1);
    // iter 1
    sgemm_kernel<<<160, 512, 0, stream>>>((const uint4*)Ph, (const uint4*)Pl,
                                          (const uint4*)Bh, (const uint4*)Bl,
                                          vth, vtl, outb, 0, 0);
    agree_kernel<<<576, 256, 0, stream>>>((const uint4*)vth, (const uint4*)vtl,
                                          Pth, Ptl, Wf, b_log, Bh, Bl, 0);
    // iter 2 -> d_out
    sgemm_kernel<<<160, 512, 0, stream>>>((const uint4*)Ph, (const uint4*)Pl,
                                          (const uint4*)Bh, (const uint4*)Bl,
                                          vth, vtl, outb, 0, 1);
}

// Round 5
// 178.300 us; speedup vs baseline: 2.8845x; 1.0339x over previous
//
#include <hip/hip_runtime.h>
#include <hip/hip_bf16.h>
#include <math.h>

// DigitCaps routing. PROVEN: P/W/out all FP32; MFMA hi/lo split path correct
// (round 7: PASS absmax 1.95e-3). Round 8: agree -> MFMA, sgemm 512thr.
// Round 9: fused agree (tgemm+reduce_bc, G in LDS), merged split -> 179 us.
// Round 10: cooperative single-kernel -> 449 us REGRESSION (grid.sync kills
//   per-XCD L2 reuse; FETCH 107 MB). Reverted.
// Round 11: sgemm block-ksplit=2 + atomic combine -> 200 us REGRESSION
//   (cross-block coordination > parallelism gain at this size). Reverted.
// Round 12: sgemm 2 K-streams/wave (2x MLP) -> 184 us NEUTRAL (loads already
//   pipelined; not latency-bound in-wave). Reverted.
// Round 13 (this): round-9 structure verbatim + XCD-aware sgemm block swizzle:
//   each XCD gets a 5c x 4b0 rectangle (footprint 7.1 -> 5.2 MB vs 4 MB L2;
//   B-panel reuse 2x -> 5x per XCD). Theory: sgemm is L2-capacity bound on
//   redundant panel reads (~184 MB/launch served from L3 today).
//   P [256][9216] f32, W [1152][10][16][8] f32, out v [256][10][16] f32.

typedef __bf16 bf16x8 __attribute__((ext_vector_type(8)));
typedef float v4f __attribute__((ext_vector_type(4)));

__device__ __forceinline__ float b2f(unsigned short u) {
    return __uint_as_float(((unsigned)u) << 16);
}
__device__ __forceinline__ unsigned short f2b(float f) {   // RNE, finite only
    unsigned x = __float_as_uint(f);
    return (unsigned short)((x + 0x7FFFu + ((x >> 16) & 1u)) >> 16);
}
__device__ __forceinline__ void split4(float4 x, unsigned short* h, unsigned short* l) {
    const float* xf = (const float*)&x;
    #pragma unroll
    for (int i = 0; i < 4; ++i) {
        h[i] = f2b(xf[i]);
        l[i] = f2b(xf[i] - b2f(h[i]));
    }
}
__device__ __forceinline__ uint2 pack4(const unsigned short* s) {
    uint2 w;
    w.x = s[0] | ((unsigned)s[1] << 16);
    w.y = s[2] | ((unsigned)s[3] << 16);
    return w;
}

// ---- merged split: blocks [0,576) split P (64b x 64k tile each);
//      blocks [576,2016) split W elementwise.
__global__ __launch_bounds__(256) void split_pw_kernel(
    const float4* __restrict__ P4, uint2* __restrict__ Ph, uint2* __restrict__ Pl,
    uint4* __restrict__ Pth, uint4* __restrict__ Ptl,
    const float4* __restrict__ W4, uint2* __restrict__ Wh, uint2* __restrict__ Wl)
{
    __shared__ unsigned short ldsH[64 * 72];
    __shared__ unsigned short ldsL[64 * 72];
    const int tid = threadIdx.x;

    if (blockIdx.x >= 576) {   // ---- W path ----
        const int idx = (blockIdx.x - 576) * 256 + tid;    // 0..368639
        unsigned short h[4], l[4];
        split4(W4[idx], h, l);
        Wh[idx] = pack4(h);
        Wl[idx] = pack4(l);
        return;
    }

    // ---- P path ----
    const int b0 = (blockIdx.x & 3) * 64;
    const int k0 = (blockIdx.x >> 2) * 64;
    #pragma unroll
    for (int j = 0; j < 4; ++j) {
        int idx = tid + j * 256;              // 0..1023
        int row = idx >> 4, col4 = idx & 15;  // b-local, k/4-local
        int g = (b0 + row) * 2304 + (k0 >> 2) + col4;
        unsigned short h[4], l[4];
        split4(P4[g], h, l);
        Ph[g] = pack4(h);
        Pl[g] = pack4(l);
        #pragma unroll
        for (int i = 0; i < 4; ++i) {
            ldsH[(col4 * 4 + i) * 72 + row] = h[i];
            ldsL[(col4 * 4 + i) * 72 + row] = l[i];
        }
    }
    __syncthreads();
    #pragma unroll
    for (int j = 0; j < 2; ++j) {
        int idx = tid + j * 256;              // 0..511
        int krow = idx >> 3, bcol = idx & 7;
        unsigned short h[8], l[8];
        #pragma unroll
        for (int i = 0; i < 8; ++i) {
            h[i] = ldsH[krow * 72 + bcol * 8 + i];
            l[i] = ldsL[krow * 72 + bcol * 8 + i];
        }
        uint4 wh, wl;
        wh.x = h[0] | ((unsigned)h[1] << 16); wh.y = h[2] | ((unsigned)h[3] << 16);
        wh.z = h[4] | ((unsigned)h[5] << 16); wh.w = h[6] | ((unsigned)h[7] << 16);
        wl.x = l[0] | ((unsigned)l[1] << 16); wl.y = l[2] | ((unsigned)l[3] << 16);
        wl.z = l[4] | ((unsigned)l[5] << 16); wl.w = l[6] | ((unsigned)l[7] << 16);
        Pth[(size_t)(k0 + krow) * 32 + (b0 >> 3) + bcol] = wh;
        Ptl[(size_t)(k0 + krow) * 32 + (b0 >> 3) + bcol] = wl;
    }
}

// ---- MFMA s-GEMM + fused squash (round-7-proven maps; 512 thr, K/8 per wave).
// Round 13: XCD-aware block->tile swizzle. With dispatch XCD = bid % 8, XCD x
// owns a 5c x 4b0 rectangle: c = (x&1)*5 + s%5, bt = (x>>1)*4 + s/5 (s=bid>>3).
// Bijective over 160 blocks; cuts per-XCD panel footprint 7.1 -> 5.2 MB.
// Writes v transposed hi/lo (vt[cd][b]) for agree A; last iter writes outb.
__global__ __launch_bounds__(512) void sgemm_kernel(
    const uint4* __restrict__ Ah, const uint4* __restrict__ Al,
    const uint4* __restrict__ Bh, const uint4* __restrict__ Bl,
    uint2* __restrict__ vth, uint2* __restrict__ vtl,
    float* __restrict__ outb, int uniform, int last)
{
    __shared__ float comb[8][64][4];
    const int tid = threadIdx.x;
    const int wave = tid >> 6, lane = tid & 63;
    const int lm = lane & 15, q = lane >> 4;
    const int xcd = blockIdx.x & 7, s0 = blockIdx.x >> 3;
    const int c = (xcd & 1) * 5 + (s0 % 5);
    const int b0 = ((xcd >> 1) * 4 + (s0 / 5)) * 16;

    const uint4* Ahp = Ah + (size_t)(b0 + lm) * 1152 + q;
    const uint4* Alp = Al + (size_t)(b0 + lm) * 1152 + q;
    const uint4* Bhp = Bh + ((size_t)q * 10 + c) * 16 + lm;
    const uint4* Blp = Bl + ((size_t)q * 10 + c) * 16 + lm;

    v4f acc = {0.f, 0.f, 0.f, 0.f};
    const int kk0 = wave * 36;
    for (int kk = kk0; kk < kk0 + 36; ++kk) {
        bf16x8 ah = __builtin_bit_cast(bf16x8, Ahp[(size_t)kk * 4]);
        bf16x8 al = __builtin_bit_cast(bf16x8, Alp[(size_t)kk * 4]);
        bf16x8 bh = __builtin_bit_cast(bf16x8, Bhp[(size_t)kk * 640]);
        bf16x8 bl = __builtin_bit_cast(bf16x8, Blp[(size_t)kk * 640]);
        acc = __builtin_amdgcn_mfma_f32_16x16x32_bf16(ah, bh, acc, 0, 0, 0);
        acc = __builtin_amdgcn_mfma_f32_16x16x32_bf16(ah, bl, acc, 0, 0, 0);
        acc = __builtin_amdgcn_mfma_f32_16x16x32_bf16(al, bh, acc, 0, 0, 0);
    }
    #pragma unroll
    for (int r = 0; r < 4; ++r) comb[wave][lane][r] = acc[r];
    __syncthreads();
    if (wave == 0) {
        float s[4], sq[4];
        #pragma unroll
        for (int r = 0; r < 4; ++r) {
            s[r] = 0.f;
            #pragma unroll
            for (int w = 0; w < 8; ++w) s[r] += comb[w][lane][r];
            if (uniform) s[r] *= 0.1f;
            sq[r] = s[r] * s[r];
        }
        #pragma unroll
        for (int m = 1; m < 16; m <<= 1) {
            #pragma unroll
            for (int r = 0; r < 4; ++r) sq[r] += __shfl_xor(sq[r], m);
        }
        float v[4];
        #pragma unroll
        for (int r = 0; r < 4; ++r) {
            const float n = sq[r];
            v[r] = s[r] * sqrtf(n) / (1.0f + n);
        }
        if (!last) {
            unsigned short h[4], l[4];
            #pragma unroll
            for (int r = 0; r < 4; ++r) {
                h[r] = f2b(v[r]);
                l[r] = f2b(v[r] - b2f(h[r]));
            }
            const int o = (c * 16 + lm) * 64 + (b0 >> 2) + q;   // uint2 units
            vth[o] = pack4(h);
            vtl[o] = pack4(l);
        } else {
            #pragma unroll
            for (int r = 0; r < 4; ++r)
                outb[((b0 + q * 4 + r) * 10 + c) * 16 + lm] = v[r];
        }
    }
}

// ---- agree: fused tgemm + reduce_bc (round-9-proven). One block per 16-ri
// tile (n0 = bid*16, covering r = 2*bid, 2*bid+1). 4 waves split K=256 ->
// 2 kk-steps each; partials summed via LDS; G kept in LDS; then reduce_bc
// runs on the two r-rows with 128 threads each; emits Bc hi/lo + b_log.
__global__ __launch_bounds__(256) void agree_kernel(
    const uint4* __restrict__ vth, const uint4* __restrict__ vtl,
    const uint4* __restrict__ Pth, const uint4* __restrict__ Ptl,
    const float* __restrict__ Wf, float* __restrict__ b_log,
    unsigned short* __restrict__ Bh, unsigned short* __restrict__ Bl, int first)
{
    __shared__ float comb2[40][4][64];   // [mt*4+reg][wave][lane] - conflict-free
    __shared__ float G_lds[160][18];     // [cd][ri-local], pad 16->18
    __shared__ float part[4][10];
    __shared__ float cl[2][10];
    const int tid = threadIdx.x;
    const int wave = tid >> 6, lane = tid & 63;
    const int lm = lane & 15, q = lane >> 4;
    const int n0 = blockIdx.x * 16;

    // ---- K-split tgemm: wave handles kk in {2*wave, 2*wave+1} ----
    v4f acc[10];
    #pragma unroll
    for (int mt = 0; mt < 10; ++mt) acc[mt] = (v4f){0.f, 0.f, 0.f, 0.f};
    #pragma unroll
    for (int kx = 0; kx < 2; ++kx) {
        const int kk = wave * 2 + kx;
        bf16x8 bh_ = __builtin_bit_cast(bf16x8, Pth[(size_t)(n0 + lm) * 32 + kk * 4 + q]);
        bf16x8 bl_ = __builtin_bit_cast(bf16x8, Ptl[(size_t)(n0 + lm) * 32 + kk * 4 + q]);
        #pragma unroll
        for (int mt = 0; mt < 10; ++mt) {
            bf16x8 ah = __builtin_bit_cast(bf16x8, vth[(size_t)(mt * 16 + lm) * 32 + kk * 4 + q]);
            bf16x8 al = __builtin_bit_cast(bf16x8, vtl[(size_t)(mt * 16 + lm) * 32 + kk * 4 + q]);
            acc[mt] = __builtin_amdgcn_mfma_f32_16x16x32_bf16(ah, bh_, acc[mt], 0, 0, 0);
            acc[mt] = __builtin_amdgcn_mfma_f32_16x16x32_bf16(ah, bl_, acc[mt], 0, 0, 0);
            acc[mt] = __builtin_amdgcn_mfma_f32_16x16x32_bf16(al, bh_, acc[mt], 0, 0, 0);
        }
    }
    #pragma unroll
    for (int mt = 0; mt < 10; ++mt)
        #pragma unroll
        for (int r = 0; r < 4; ++r)
            comb2[mt * 4 + r][wave][lane] = acc[mt][r];
    __syncthreads();
    // ---- sum wave partials -> G_lds. Wave w owns c40 = w*10 .. w*10+9 ----
    #pragma unroll
    for (int j = 0; j < 10; ++j) {
        const int c40 = wave * 10 + j;
        float s_ = comb2[c40][0][lane] + comb2[c40][1][lane]
                 + comb2[c40][2][lane] + comb2[c40][3][lane];
        const int mt = c40 >> 2, reg = c40 & 3;
        G_lds[mt * 16 + q * 4 + reg][lm] = s_;     // G[cd][ri = n0+lm]
    }
    __syncthreads();

    // ---- reduce_bc phase (proven logic; 128 threads per r-row) ----
    const int rl = tid >> 7;        // 0..1 -> which r this half-block owns
    const int t = tid & 127;        // d*8+i
    const int r = (n0 >> 3) + rl;
    const int wid2 = tid >> 6;      // 0..3

    float wv[10], a[10];
    #pragma unroll
    for (int c = 0; c < 10; ++c) {
        wv[c] = Wf[((size_t)r * 10 + c) * 128 + t];
        float g = G_lds[c * 16 + (t >> 3)][rl * 8 + (t & 7)];
        a[c] = wv[c] * g;
    }
    #pragma unroll
    for (int m = 1; m < 64; m <<= 1) {
        #pragma unroll
        for (int c = 0; c < 10; ++c) a[c] += __shfl_xor(a[c], m);
    }
    if (lane == 0) {
        #pragma unroll
        for (int c = 0; c < 10; ++c) part[wid2][c] = a[c];
    }
    __syncthreads();
    if (t < 10) {    // threads 0..9 (rl=0) and 128..137 (rl=1)
        float s_ = (part[rl * 2][t] + part[rl * 2 + 1][t]) * (1.0f / 256.0f);
        float bn = (first ? 0.f : b_log[r * 10 + t]) + s_;
        b_log[r * 10 + t] = bn;
        part[rl * 2][t] = bn;            // reuse as softmax scratch
    }
    __syncthreads();
    if (t < 10) {
        float mx = part[rl * 2][0];
        #pragma unroll
        for (int j = 1; j < 10; ++j) mx = fmaxf(mx, part[rl * 2][j]);
        float den = 0.f;
        #pragma unroll
        for (int j = 0; j < 10; ++j) den += __expf(part[rl * 2][j] - mx);
        cl[rl][t] = __expf(part[rl * 2][t] - mx) / den;
    }
    __syncthreads();
    #pragma unroll
    for (int c = 0; c < 10; ++c) {
        float x = cl[rl][c] * wv[c];
        unsigned short h = f2b(x);
        Bh[((size_t)r * 10 + c) * 128 + t] = h;
        Bl[((size_t)r * 10 + c) * 128 + t] = f2b(x - b2f(h));
    }
}

extern "C" void kernel_launch(void* const* d_in, const int* in_sizes, int n_in,
                              void* d_out, int out_size, void* d_ws, size_t ws_size,
                              hipStream_t stream)
{
    const float4* P4 = (const float4*)d_in[0];
    const float4* W4 = (const float4*)d_in[1];
    char* wsb = (char*)d_ws;
    // BYTE offsets (audited, all 16B-aligned):
    float* b_log = (float*)(wsb + 0);              // 46080 B
    uint2* vth   = (uint2*)(wsb + 131072);         // 81920 B
    uint2* vtl   = (uint2*)(wsb + 262144);         // 81920 B
    uint2* Ph    = (uint2*)(wsb + 393216);         // 4718592 B
    uint2* Pl    = (uint2*)(wsb + 5242880);        // 4718592 B
    uint4* Pth   = (uint4*)(wsb + 10485760);       // 4718592 B
    uint4* Ptl   = (uint4*)(wsb + 15728640);       // 4718592 B
    uint2* Wh    = (uint2*)(wsb + 20971520);       // 2949120 B
    uint2* Wl    = (uint2*)(wsb + 25165824);       // 2949120 B
    unsigned short* Bh = (unsigned short*)(wsb + 29360128);  // 2949120 B
    unsigned short* Bl = (unsigned short*)(wsb + 33554432);  // 2949120 B
    float* outb  = (float*)d_out;
    const float* Wf = (const float*)W4;

    split_pw_kernel<<<2016, 256, 0, stream>>>(P4, Ph, Pl, Pth, Ptl, W4, Wh, Wl);

    // iter 0: B = W, uniform c = 0.1 post-MFMA
    sgemm_kernel<<<160, 512, 0, stream>>>((const uint4*)Ph, (const uint4*)Pl,
                                          (const uint4*)Wh, (const uint4*)Wl,
                                          vth, vtl, outb, 1, 0);
    agree_kernel<<<576, 256, 0, stream>>>((const uint4*)vth, (const uint4*)vtl,
                                          Pth, Ptl, Wf, b_log, Bh, Bl, 1);
    // iter 1
    sgemm_kernel<<<160, 512, 0, stream>>>((const uint4*)Ph, (const uint4*)Pl,
                                          (const uint4*)Bh, (const uint4*)Bl,
                                          vth, vtl, outb, 0, 0);
    agree_kernel<<<576, 256, 0, stream>>>((const uint4*)vth, (const uint4*)vtl,
                                          Pth, Ptl, Wf, b_log, Bh, Bl, 0);
    // iter 2 -> d_out
    sgemm_kernel<<<160, 512, 0, stream>>>((const uint4*)Ph, (const uint4*)Pl,
                                          (const uint4*)Bh, (const uint4*)Bl,
                                          vth, vtl, outb, 0, 1);
}